// Round 10
// baseline (646.348 us; speedup 1.0000x reference)
//
#include <hip/hip_runtime.h>
#include <math.h>

#define N_NODES 50000
#define N_EDGES 800000
#define CDIM    128
#define GDIM    128
#define L0DIM   512
#define L1DIM   256

typedef unsigned int uint;
typedef unsigned short ushort;
typedef __attribute__((ext_vector_type(8))) short short8;
typedef __attribute__((ext_vector_type(4))) float f32x4;
typedef __attribute__((ext_vector_type(4))) uint u32x4;

// S = log2(e)/sqrt(128), folded into stored q
#define QSCALE 0.12751744f

__device__ inline ushort f2bf(float f) {
  uint u = __float_as_uint(f);
  uint r = (u + 0x7fffu + ((u >> 16) & 1u)) >> 16;
  return (ushort)r;
}
__device__ inline float bflo(uint u) { return __uint_as_float(u << 16); }
__device__ inline float bfhi(uint u) { return __uint_as_float(u & 0xffff0000u); }
__device__ inline uint pack2bf(float a, float b) {
  return (uint)f2bf(a) | ((uint)f2bf(b) << 16);
}
// non-temporal load: single-use streams must not evict the KV working set
template <typename T>
__device__ inline T ntload(const T* p) { return __builtin_nontemporal_load(p); }

// ============================ CSR build =================================
__global__ void hist_kernel(const int* __restrict__ dst, int* counts, int E) {
  int e = blockIdx.x * 256 + threadIdx.x;
  if (e < E) atomicAdd(&counts[ntload(dst + e)], 1);
}

__global__ void scan_blocks(const int* __restrict__ counts, int* excl, int* bsums, int N) {
  __shared__ int s[1024];
  int tid = threadIdx.x;
  int i = blockIdx.x * 1024 + tid;
  int v = (i < N) ? counts[i] : 0;
  s[tid] = v;
  __syncthreads();
  for (int off = 1; off < 1024; off <<= 1) {
    int t = (tid >= off) ? s[tid - off] : 0;
    __syncthreads();
    s[tid] += t;
    __syncthreads();
  }
  if (i < N) excl[i] = s[tid] - v;
  if (tid == 1023) bsums[blockIdx.x] = s[1023];
}

// fused: per-block bsums-prefix reduce + indptr write + cursor zero + gp zero
__global__ void scan_add(const int* __restrict__ excl, const int* __restrict__ bsums,
                         int* indptr, int* cursor, float* gp, int N, int E) {
  __shared__ int base_s;
  int tid = threadIdx.x;
  if (tid < 64) {
    int v = (tid < (int)blockIdx.x) ? bsums[tid] : 0;  // blockIdx.x <= 48 < nscan
#pragma unroll
    for (int off = 1; off < 64; off <<= 1) v += __shfl_xor(v, off);
    if (tid == 0) base_s = v;
  }
  __syncthreads();
  int base = base_s;
  int i = blockIdx.x * 1024 + tid;
  if (i < N) { indptr[i] = excl[i] + base; cursor[i] = 0; }
  if (i == 0) indptr[N] = E;
  if (i < GDIM * CDIM) gp[i] = 0.f;
}

// csr_sa[i] = {ax, ay, az, bits(src)} — one 16B record per edge
__global__ void scatter2_kernel(const int* __restrict__ dst, const int* __restrict__ src,
                                const float* __restrict__ attr,
                                const int* __restrict__ indptr,
                                int* cursor, float4* csr_sa, int E) {
  int e = blockIdx.x * 256 + threadIdx.x;
  if (e < E) {
    int d = ntload(dst + e);
    int pos = atomicAdd(&cursor[d], 1);
    int i = indptr[d] + pos;
    float4 v;
    v.x = ntload(attr + e * 3 + 0);
    v.y = ntload(attr + e * 3 + 1);
    v.z = ntload(attr + e * 3 + 2);
    v.w = __int_as_float(ntload(src + e));
    csr_sa[i] = v;
  }
}

// ===================== layer 0 (din=4) q/kv/skip ========================
// q stored bf16 pre-scaled by QSCALE; skip h stored bf16
__global__ void l0_qkvs(const float* __restrict__ x,
                        const float* __restrict__ Wq, const float* __restrict__ bq,
                        const float* __restrict__ Wk, const float* __restrict__ bk,
                        const float* __restrict__ Wv, const float* __restrict__ bv,
                        const float* __restrict__ Ws, const float* __restrict__ bs,
                        ushort* __restrict__ q, ushort* __restrict__ kvb,
                        ushort* __restrict__ hs, int N) {
  __shared__ float W[4][4][128];
  __shared__ float B[4][128];
  int tid = threadIdx.x;
  for (int i = tid; i < 4 * 128; i += 256) {
    W[0][i >> 7][i & 127] = Wq[i];
    W[1][i >> 7][i & 127] = Wk[i];
    W[2][i >> 7][i & 127] = Wv[i];
    W[3][i >> 7][i & 127] = Ws[i];
  }
  for (int i = tid; i < 128; i += 256) {
    B[0][i] = bq[i]; B[1][i] = bk[i]; B[2][i] = bv[i]; B[3][i] = bs[i];
  }
  __syncthreads();
  int gid = blockIdx.x * 256 + tid;
  int n = gid >> 7, c = gid & 127;
  if (n >= N) return;
  float x0 = ntload(x + n * 4 + 0), x1 = ntload(x + n * 4 + 1);
  float x2 = ntload(x + n * 4 + 2), x3 = ntload(x + n * 4 + 3);
  float qv = x0 * W[0][0][c] + x1 * W[0][1][c] + x2 * W[0][2][c] + x3 * W[0][3][c] + B[0][c];
  float kv = x0 * W[1][0][c] + x1 * W[1][1][c] + x2 * W[1][2][c] + x3 * W[1][3][c] + B[1][c];
  float vv = x0 * W[2][0][c] + x1 * W[2][1][c] + x2 * W[2][2][c] + x3 * W[2][3][c] + B[2][c];
  float sv = x0 * W[3][0][c] + x1 * W[3][1][c] + x2 * W[3][2][c] + x3 * W[3][3][c] + B[3][c];
  q[(size_t)n * 128 + c] = f2bf(qv * QSCALE);
  kvb[(size_t)n * 256 + c]       = f2bf(kv);
  kvb[(size_t)n * 256 + 128 + c] = f2bf(vv);
  hs[(size_t)n * 128 + c] = f2bf(sv);
}

// ============== W -> bf16 transposed: wt[z][c][k] = W_z[k][c] =============
__global__ void prep_w(const float* __restrict__ Wq, const float* __restrict__ Wk,
                       const float* __restrict__ Wv, const float* __restrict__ Ws,
                       ushort* __restrict__ wt) {
  int idx = blockIdx.x * 256 + threadIdx.x;  // 4*16384
  int z = idx >> 14, rem = idx & 16383;
  int k_ = rem >> 7, c_ = rem & 127;
  const float* W = (z == 0) ? Wq : (z == 1) ? Wk : (z == 2) ? Wv : Ws;
  wt[z * 16384 + c_ * 128 + k_] = f2bf(W[k_ * 128 + c_]);
}

// ==== layers 1-2 GEMM via MFMA, z on grid, A input bf16, skip out bf16 ===
#define LDA 136
__global__ __launch_bounds__(256) void gemm_mfma(
    const ushort* __restrict__ H16, const ushort* __restrict__ wtg,
    const float* __restrict__ bq, const float* __restrict__ bk,
    const float* __restrict__ bv, const float* __restrict__ bs,
    ushort* __restrict__ q, ushort* __restrict__ kvb,
    ushort* __restrict__ hs, int N) {
  int z = blockIdx.z;
  const float* bb = (z == 0) ? bq : (z == 1) ? bk : (z == 2) ? bv : bs;
  __shared__ ushort Alds[64 * LDA];
  __shared__ ushort Wlds[128 * LDA];
  int tid = threadIdx.x;
  int n0 = blockIdx.x * 64;

  {
    const uint* wg = (const uint*)(wtg + z * 16384);
    uint* wl = (uint*)Wlds;
    for (int i = tid; i < 8192; i += 256) {
      int c_ = i >> 6, kp = i & 63;
      wl[c_ * (LDA / 2) + kp] = wg[c_ * 64 + kp];
    }
  }
  {  // A tile: direct bf16 copy, non-temporal (each row read by one block)
    const uint* hg = (const uint*)H16;
    uint* al = (uint*)Alds;
    for (int i = tid; i < 4096; i += 256) {
      int r = i >> 6, kp = i & 63;
      int grow = n0 + r; grow = (grow < N) ? grow : (N - 1);
      al[r * (LDA / 2) + kp] = ntload(hg + (size_t)grow * 64 + kp);
    }
  }
  __syncthreads();

  int w = tid >> 6, lane = tid & 63;
  int m_ = lane & 15, quad = lane >> 4;
  f32x4 acc[8];
#pragma unroll
  for (int ct = 0; ct < 8; ct++) acc[ct] = 0.f;

#pragma unroll
  for (int kc = 0; kc < 4; kc++) {
    short8 af = *(const short8*)&Alds[(w * 16 + m_) * LDA + kc * 32 + quad * 8];
#pragma unroll
    for (int ct = 0; ct < 8; ct++) {
      short8 bf = *(const short8*)&Wlds[(ct * 16 + m_) * LDA + kc * 32 + quad * 8];
      acc[ct] = __builtin_amdgcn_mfma_f32_16x16x32_bf16(af, bf, acc[ct], 0, 0, 0);
    }
  }

#pragma unroll
  for (int ct = 0; ct < 8; ct++) {
    int col = ct * 16 + m_;
    float bcol = bb[col];
#pragma unroll
    for (int reg = 0; reg < 4; reg++) {
      int n = n0 + w * 16 + quad * 4 + reg;
      if (n < N) {
        float o = acc[ct][reg] + bcol;
        if (z == 0)      q[(size_t)n * 128 + col] = f2bf(o * QSCALE);
        else if (z == 3) hs[(size_t)n * 128 + col] = f2bf(o);
        else             kvb[(size_t)n * 256 + ((z == 2) ? 128 : 0) + col] = f2bf(o);
      }
    }
  }
}

// ====== fused attention v13: nt loads for single-use streams =============
// csr_sa / q / hskip are read exactly once per dispatch -> non-temporal,
// preserving L2 capacity for the KV gather working set (the reuse).
__global__ __launch_bounds__(256) void attn_fused(
    const ushort* __restrict__ q, const ushort* __restrict__ kv,
    const int* __restrict__ indptr, const float4* __restrict__ csr_sa,
    const float* __restrict__ We,
    const ushort* __restrict__ hskip, ushort* __restrict__ hout, int N) {
  __shared__ float WeS[384];
  int tid = threadIdx.x;
  for (int i = tid; i < 384; i += 256) WeS[i] = We[i];
  __syncthreads();
  int lane = tid & 63;
  int n = blockIdx.x * 4 + (tid >> 6);
  if (n >= N) return;
  int g = lane >> 4, gl = lane & 15;
  int c = gl * 8;  // 8 channels per lane
  // q is bf16, already scaled by log2(e)/sqrt(128)
  u32x4 qr = ntload((const u32x4*)&q[(size_t)n * 128 + c]);
  float qv[8] = {bflo(qr.x), bfhi(qr.x), bflo(qr.y), bfhi(qr.y),
                 bflo(qr.z), bfhi(qr.z), bflo(qr.w), bfhi(qr.w)};
  float we0[8], we1[8], we2[8];
#pragma unroll
  for (int j = 0; j < 8; j++) {
    we0[j] = WeS[c + j]; we1[j] = WeS[128 + c + j]; we2[j] = WeS[256 + c + j];
  }
  // t = We^T (S*q)  (identical in all 4 groups)
  float t0 = 0.f, t1 = 0.f, t2 = 0.f;
#pragma unroll
  for (int j = 0; j < 8; j++) {
    t0 = fmaf(we0[j], qv[j], t0);
    t1 = fmaf(we1[j], qv[j], t1);
    t2 = fmaf(we2[j], qv[j], t2);
  }
#pragma unroll
  for (int off = 1; off < 16; off <<= 1) {
    t0 += __shfl_xor(t0, off);
    t1 += __shfl_xor(t1, off);
    t2 += __shfl_xor(t2, off);
  }

  u32x4 skr = ntload((const u32x4*)&hskip[(size_t)n * 128 + c]);
  float sk[8] = {bflo(skr.x), bfhi(skr.x), bflo(skr.y), bfhi(skr.y),
                 bflo(skr.z), bfhi(skr.z), bflo(skr.w), bfhi(skr.w)};
  int beg = indptr[n], end = indptr[n + 1];

  if (end > beg) {
    float d = 0.f;
    float sa0 = 0.f, sa1 = 0.f, sa2 = 0.f;
    float acc[8];
#pragma unroll
    for (int j = 0; j < 8; j++) acc[j] = 0.f;
    const uint* kvw = (const uint*)kv;
    const f32x4* sa_p = (const f32x4*)csr_sa;
    const int endm1 = end - 1;

    // branch-free prefetch for edge pair (i, i+4), indices clamped in-bounds
    int i = beg + g;
    int pA = (i     < end) ? i     : endm1;
    int pB = (i + 4 < end) ? i + 4 : endm1;
    f32x4 saA = ntload(sa_p + pA);
    f32x4 saB = ntload(sa_p + pB);

    for (; i < end; i += 8) {
      f32x4 saAc = saA, saBc = saB;
      float wB = ((i + 4) < end) ? 1.f : 0.f;
      // prefetch next pair (always valid clamped indices, no branches)
      int nn = i + 8;
      int qA = (nn     < end) ? nn     : endm1;
      int qB = (nn + 4 < end) ? nn + 4 : endm1;
      saA = ntload(sa_p + qA);
      saB = ntload(sa_p + qB);
      int sjAc = __float_as_int(saAc.w);
      int sjBc = __float_as_int(saBc.w);
      // issue all 4 row loads up front (2 edges x K,V) — ALLOCATING (reuse)
      const uint4* kpA = (const uint4*)(kvw + (size_t)sjAc * 128);
      const uint4* kpB = (const uint4*)(kvw + (size_t)sjBc * 128);
      uint4 krA = kpA[gl];
      uint4 krB = kpB[gl];
      uint4 vrA = kpA[16 + gl];
      uint4 vrB = kpB[16 + gl];
      float kxA[8], kxB[8];
      kxA[0] = bflo(krA.x); kxA[1] = bfhi(krA.x); kxA[2] = bflo(krA.y); kxA[3] = bfhi(krA.y);
      kxA[4] = bflo(krA.z); kxA[5] = bfhi(krA.z); kxA[6] = bflo(krA.w); kxA[7] = bfhi(krA.w);
      kxB[0] = bflo(krB.x); kxB[1] = bfhi(krB.x); kxB[2] = bflo(krB.y); kxB[3] = bfhi(krB.y);
      kxB[4] = bflo(krB.z); kxB[5] = bfhi(krB.z); kxB[6] = bflo(krB.w); kxB[7] = bfhi(krB.w);
      float pAv = 0.f, pBv = 0.f;
#pragma unroll
      for (int j = 0; j < 8; j++) {
        pAv = fmaf(qv[j], kxA[j], pAv);
        pBv = fmaf(qv[j], kxB[j], pBv);
      }
      // two independent 4-step reductions, interleaved
      pAv += __shfl_xor(pAv, 1);  pBv += __shfl_xor(pBv, 1);
      pAv += __shfl_xor(pAv, 2);  pBv += __shfl_xor(pBv, 2);
      pAv += __shfl_xor(pAv, 4);  pBv += __shfl_xor(pBv, 4);
      pAv += __shfl_xor(pAv, 8);  pBv += __shfl_xor(pBv, 8);
      pAv = fmaf(saAc.x, t0, pAv);
      pBv = fmaf(saBc.x, t0, pBv);
      pAv = fmaf(saAc.y, t1, pAv);
      pBv = fmaf(saBc.y, t1, pBv);
      pAv = fmaf(saAc.z, t2, pAv);
      pBv = fmaf(saBc.z, t2, pBv);
      float aA = __builtin_amdgcn_exp2f(pAv);
      float aB = wB * __builtin_amdgcn_exp2f(pBv);  // tail-B contributes 0
      d += aA + aB;
      sa0 = fmaf(aA, saAc.x, sa0); sa0 = fmaf(aB, saBc.x, sa0);
      sa1 = fmaf(aA, saAc.y, sa1); sa1 = fmaf(aB, saBc.y, sa1);
      sa2 = fmaf(aA, saAc.z, sa2); sa2 = fmaf(aB, saBc.z, sa2);
      float vxA[8], vxB[8];
      vxA[0] = bflo(vrA.x); vxA[1] = bfhi(vrA.x); vxA[2] = bflo(vrA.y); vxA[3] = bfhi(vrA.y);
      vxA[4] = bflo(vrA.z); vxA[5] = bfhi(vrA.z); vxA[6] = bflo(vrA.w); vxA[7] = bfhi(vrA.w);
      vxB[0] = bflo(vrB.x); vxB[1] = bfhi(vrB.x); vxB[2] = bflo(vrB.y); vxB[3] = bfhi(vrB.y);
      vxB[4] = bflo(vrB.z); vxB[5] = bfhi(vrB.z); vxB[6] = bflo(vrB.w); vxB[7] = bfhi(vrB.w);
#pragma unroll
      for (int j = 0; j < 8; j++) {
        acc[j] = fmaf(aA, vxA[j], acc[j]);
        acc[j] = fmaf(aB, vxB[j], acc[j]);
      }
    }
    // merge the 4 groups' partial sums (pure adds — no rescale needed)
#pragma unroll
    for (int off = 16; off < 64; off <<= 1) {
      d += __shfl_xor(d, off);
      sa0 += __shfl_xor(sa0, off);
      sa1 += __shfl_xor(sa1, off);
      sa2 += __shfl_xor(sa2, off);
#pragma unroll
      for (int j = 0; j < 8; j++) acc[j] += __shfl_xor(acc[j], off);
    }
    float inv = 1.f / d;
#pragma unroll
    for (int j = 0; j < 8; j++) {
      float ecorr = sa0 * we0[j] + sa1 * we1[j] + sa2 * we2[j];
      sk[j] += (acc[j] + ecorr) * inv;
    }
  }
#pragma unroll
  for (int j = 0; j < 8; j++) sk[j] = (sk[j] > 0.f) ? sk[j] : 0.01f * sk[j];
  if (g == 0) {
    uint4 hb;
    hb.x = pack2bf(sk[0], sk[1]);
    hb.y = pack2bf(sk[2], sk[3]);
    hb.z = pack2bf(sk[4], sk[5]);
    hb.w = pack2bf(sk[6], sk[7]);
    *(uint4*)&hout[(size_t)n * 128 + c] = hb;
  }
}

// ======================= pool (batch is sorted, bf16 input) =============
__global__ void pool_kernel(const ushort* __restrict__ h16, const int* __restrict__ batch,
                            float* __restrict__ gout, int N) {
  int tid = threadIdx.x;
  int sub = tid >> 6;
  int c = 2 * (tid & 63);
  int n0 = blockIdx.x * 64 + sub * 16;
  if (n0 >= N) return;
  int n1 = min(n0 + 16, N);
  float a0 = 0.f, a1 = 0.f;
  int cur = ntload(batch + n0);
  for (int n = n0; n < n1; n++) {
    int b = ntload(batch + n);
    if (b != cur) {
      atomicAdd(&gout[cur * 128 + c], a0);
      atomicAdd(&gout[cur * 128 + c + 1], a1);
      a0 = 0.f; a1 = 0.f; cur = b;
    }
    uint hv = ntload((const uint*)&h16[(size_t)n * 128 + c]);
    a0 += bflo(hv); a1 += bfhi(hv);
  }
  atomicAdd(&gout[cur * 128 + c], a0);
  atomicAdd(&gout[cur * 128 + c + 1], a1);
}

// ===================== fused MLP head (one block / graph) ================
__global__ __launch_bounds__(256) void mlp_fused(
    const float* __restrict__ gp,
    const float* __restrict__ Wl0, const float* __restrict__ bl0,
    const float* __restrict__ Wl1, const float* __restrict__ bl1,
    const float* __restrict__ Wl2, const float* __restrict__ bl2,
    float* __restrict__ out) {
  int g = blockIdx.x;
  int tid = threadIdx.x;
  __shared__ float xin[CDIM];
  __shared__ float h1[L0DIM];
  __shared__ float h2[L1DIM];
  __shared__ float r0s[4], r1s[4];
  if (tid < CDIM) xin[tid] = gp[g * CDIM + tid];
  __syncthreads();
  for (int c = tid; c < L0DIM; c += 256) {
    float a0 = 0.f, a1 = 0.f, a2 = 0.f, a3 = 0.f;
#pragma unroll 4
    for (int kk = 0; kk < CDIM; kk += 4) {
      a0 = fmaf(xin[kk + 0], Wl0[(kk + 0) * L0DIM + c], a0);
      a1 = fmaf(xin[kk + 1], Wl0[(kk + 1) * L0DIM + c], a1);
      a2 = fmaf(xin[kk + 2], Wl0[(kk + 2) * L0DIM + c], a2);
      a3 = fmaf(xin[kk + 3], Wl0[(kk + 3) * L0DIM + c], a3);
    }
    h1[c] = fmaxf((a0 + a1) + (a2 + a3) + bl0[c], 0.f);
  }
  __syncthreads();
  {
    int c = tid;
    float a0 = 0.f, a1 = 0.f, a2 = 0.f, a3 = 0.f;
#pragma unroll 4
    for (int kk = 0; kk < L0DIM; kk += 4) {
      a0 = fmaf(h1[kk + 0], Wl1[(kk + 0) * L1DIM + c], a0);
      a1 = fmaf(h1[kk + 1], Wl1[(kk + 1) * L1DIM + c], a1);
      a2 = fmaf(h1[kk + 2], Wl1[(kk + 2) * L1DIM + c], a2);
      a3 = fmaf(h1[kk + 3], Wl1[(kk + 3) * L1DIM + c], a3);
    }
    h2[c] = fmaxf((a0 + a1) + (a2 + a3) + bl1[c], 0.f);
  }
  __syncthreads();
  float p0 = h2[tid] * Wl2[tid * 2 + 0];
  float p1 = h2[tid] * Wl2[tid * 2 + 1];
#pragma unroll
  for (int off = 32; off > 0; off >>= 1) {
    p0 += __shfl_down(p0, off);
    p1 += __shfl_down(p1, off);
  }
  int wv = tid >> 6, ln = tid & 63;
  if (ln == 0) { r0s[wv] = p0; r1s[wv] = p1; }
  __syncthreads();
  if (tid == 0) out[g * 2 + 0] = r0s[0] + r0s[1] + r0s[2] + r0s[3] + bl2[0];
  if (tid == 1) out[g * 2 + 1] = r1s[0] + r1s[1] + r1s[2] + r1s[3] + bl2[1];
}

// ============================== launch ==================================
extern "C" void kernel_launch(void* const* d_in, const int* in_sizes, int n_in,
                              void* d_out, int out_size, void* d_ws, size_t ws_size,
                              hipStream_t stream) {
  const int N = N_NODES, E = N_EDGES;
  const float* x    = (const float*)d_in[0];
  const int*   ei   = (const int*)d_in[1];
  const float* attr = (const float*)d_in[2];
  const int*   batch= (const int*)d_in[3];
  const int* src = ei;
  const int* dst = ei + E;

  const float *Wq0 = (const float*)d_in[4],  *bq0 = (const float*)d_in[5];
  const float *Wk0 = (const float*)d_in[6],  *bk0 = (const float*)d_in[7];
  const float *Wv0 = (const float*)d_in[8],  *bv0 = (const float*)d_in[9];
  const float *We0 = (const float*)d_in[10];
  const float *Ws0 = (const float*)d_in[11], *bs0 = (const float*)d_in[12];
  const float *Wq1 = (const float*)d_in[13], *bq1 = (const float*)d_in[14];
  const float *Wk1 = (const float*)d_in[15], *bk1 = (const float*)d_in[16];
  const float *Wv1 = (const float*)d_in[17], *bv1 = (const float*)d_in[18];
  const float *We1 = (const float*)d_in[19];
  const float *Ws1 = (const float*)d_in[20], *bs1 = (const float*)d_in[21];
  const float *Wl0 = (const float*)d_in[22], *bl0 = (const float*)d_in[23];
  const float *Wl1 = (const float*)d_in[24], *bl1 = (const float*)d_in[25];
  const float *Wl2 = (const float*)d_in[26], *bl2 = (const float*)d_in[27];

  size_t off = 0;
  auto carve = [&](size_t bytes) {
    void* p = (char*)d_ws + off;
    off += (bytes + 255) & ~(size_t)255;
    return p;
  };
  ushort* hsA      = (ushort*)carve((size_t)N * CDIM * 2);  // skip (bf16)
  ushort* hsB      = (ushort*)carve((size_t)N * CDIM * 2);
  ushort* hA16     = (ushort*)carve((size_t)N * CDIM * 2);  // h (bf16)
  ushort* hB16     = (ushort*)carve((size_t)N * CDIM * 2);
  ushort* qb       = (ushort*)carve((size_t)N * CDIM * 2);
  ushort* kvb      = (ushort*)carve((size_t)N * 256 * 2);
  int*    indptr   = (int*)carve((size_t)(N + 1) * 4);
  float4* csr_sa   = (float4*)carve((size_t)E * 16);
  int*    cc       = (int*)carve((size_t)2 * N * 4);   // counts | cursor
  int*    counts   = cc;
  int*    cursor   = cc + N;
  int*    excl     = (int*)carve((size_t)N * 4);
  int*    bsums    = (int*)carve((size_t)64 * 4);
  ushort* wt1      = (ushort*)carve((size_t)4 * 16384 * 2);
  float*  gp       = (float*)carve((size_t)GDIM * CDIM * 4);

  hipMemsetAsync(counts, 0, (size_t)N * 4, stream);

  int nscan = (N + 1023) / 1024;
  hist_kernel<<<(E + 255) / 256, 256, 0, stream>>>(dst, counts, E);
  scan_blocks<<<nscan, 1024, 0, stream>>>(counts, excl, bsums, N);
  scan_add<<<nscan, 1024, 0, stream>>>(excl, bsums, indptr, cursor, gp, N, E);
  scatter2_kernel<<<(E + 255) / 256, 256, 0, stream>>>(dst, src, attr, indptr, cursor,
                                                       csr_sa, E);
  prep_w<<<256, 256, 0, stream>>>(Wq1, Wk1, Wv1, Ws1, wt1);

  int naBlocks = (N + 3) / 4;
  dim3 gemmGrid((N + 63) / 64, 1, 4);

  // ---- layer 0 (din=4) ----
  l0_qkvs<<<(N * 128 + 255) / 256, 256, 0, stream>>>(
      x, Wq0, bq0, Wk0, bk0, Wv0, bv0, Ws0, bs0, qb, kvb, hsA, N);
  attn_fused<<<naBlocks, 256, 0, stream>>>(qb, kvb, indptr, csr_sa, We0, hsA, hA16, N);

  // ---- layer 1 (shared weights) ----
  gemm_mfma<<<gemmGrid, 256, 0, stream>>>(hA16, wt1, bq1, bk1, bv1, bs1, qb, kvb, hsB, N);
  attn_fused<<<naBlocks, 256, 0, stream>>>(qb, kvb, indptr, csr_sa, We1, hsB, hB16, N);

  // ---- layer 2 (same weights) ----
  gemm_mfma<<<gemmGrid, 256, 0, stream>>>(hB16, wt1, bq1, bk1, bv1, bs1, qb, kvb, hsA, N);
  attn_fused<<<naBlocks, 256, 0, stream>>>(qb, kvb, indptr, csr_sa, We1, hsA, hA16, N);

  // ---- pool + fused MLP ----
  pool_kernel<<<(N + 63) / 64, 256, 0, stream>>>(hA16, batch, gp, N);
  mlp_fused<<<GDIM, 256, 0, stream>>>(gp, Wl0, bl0, Wl1, bl1, Wl2, bl2, (float*)d_out);
}

// Round 11
// 555.595 us; speedup vs baseline: 1.1633x; 1.1633x over previous
//
#include <hip/hip_runtime.h>
#include <math.h>

#define N_NODES 50000
#define N_EDGES 800000
#define CDIM    128
#define GDIM    128
#define L0DIM   512
#define L1DIM   256

typedef unsigned int uint;
typedef unsigned short ushort;
typedef __attribute__((ext_vector_type(8))) short short8;
typedef __attribute__((ext_vector_type(4))) float f32x4;

// S = log2(e)/sqrt(128), folded into stored q
#define QSCALE 0.12751744f

__device__ inline ushort f2bf(float f) {
  uint u = __float_as_uint(f);
  uint r = (u + 0x7fffu + ((u >> 16) & 1u)) >> 16;
  return (ushort)r;
}
__device__ inline float bflo(uint u) { return __uint_as_float(u << 16); }
__device__ inline float bfhi(uint u) { return __uint_as_float(u & 0xffff0000u); }
__device__ inline uint pack2bf(float a, float b) {
  return (uint)f2bf(a) | ((uint)f2bf(b) << 16);
}

// ============================ CSR build =================================
__global__ void hist_kernel(const int* __restrict__ dst, int* counts, int E) {
  int e = blockIdx.x * 256 + threadIdx.x;
  if (e < E) atomicAdd(&counts[dst[e]], 1);
}

__global__ void scan_blocks(const int* __restrict__ counts, int* excl, int* bsums, int N) {
  __shared__ int s[1024];
  int tid = threadIdx.x;
  int i = blockIdx.x * 1024 + tid;
  int v = (i < N) ? counts[i] : 0;
  s[tid] = v;
  __syncthreads();
  for (int off = 1; off < 1024; off <<= 1) {
    int t = (tid >= off) ? s[tid - off] : 0;
    __syncthreads();
    s[tid] += t;
    __syncthreads();
  }
  if (i < N) excl[i] = s[tid] - v;
  if (tid == 1023) bsums[blockIdx.x] = s[1023];
}

// fused: per-block bsums-prefix reduce + indptr write + cursor zero + gp zero
__global__ void scan_add(const int* __restrict__ excl, const int* __restrict__ bsums,
                         int* indptr, int* cursor, float* gp, int N, int E) {
  __shared__ int base_s;
  int tid = threadIdx.x;
  if (tid < 64) {
    int v = (tid < (int)blockIdx.x) ? bsums[tid] : 0;  // blockIdx.x <= 48 < nscan
#pragma unroll
    for (int off = 1; off < 64; off <<= 1) v += __shfl_xor(v, off);
    if (tid == 0) base_s = v;
  }
  __syncthreads();
  int base = base_s;
  int i = blockIdx.x * 1024 + tid;
  if (i < N) { indptr[i] = excl[i] + base; cursor[i] = 0; }
  if (i == 0) indptr[N] = E;
  if (i < GDIM * CDIM) gp[i] = 0.f;
}

// csr_sa[i] = {ax, ay, az, bits(src)} — one 16B record per edge
__global__ void scatter2_kernel(const int* __restrict__ dst, const int* __restrict__ src,
                                const float* __restrict__ attr,
                                const int* __restrict__ indptr,
                                int* cursor, float4* csr_sa, int E) {
  int e = blockIdx.x * 256 + threadIdx.x;
  if (e < E) {
    int d = dst[e];
    int pos = atomicAdd(&cursor[d], 1);
    int i = indptr[d] + pos;
    float4 v;
    v.x = attr[e * 3 + 0];
    v.y = attr[e * 3 + 1];
    v.z = attr[e * 3 + 2];
    v.w = __int_as_float(src[e]);
    csr_sa[i] = v;
  }
}

// ===================== layer 0 (din=4) q/kv/skip ========================
// q stored bf16 pre-scaled by QSCALE; skip h stored bf16
__global__ void l0_qkvs(const float* __restrict__ x,
                        const float* __restrict__ Wq, const float* __restrict__ bq,
                        const float* __restrict__ Wk, const float* __restrict__ bk,
                        const float* __restrict__ Wv, const float* __restrict__ bv,
                        const float* __restrict__ Ws, const float* __restrict__ bs,
                        ushort* __restrict__ q, ushort* __restrict__ kvb,
                        ushort* __restrict__ hs, int N) {
  __shared__ float W[4][4][128];
  __shared__ float B[4][128];
  int tid = threadIdx.x;
  for (int i = tid; i < 4 * 128; i += 256) {
    W[0][i >> 7][i & 127] = Wq[i];
    W[1][i >> 7][i & 127] = Wk[i];
    W[2][i >> 7][i & 127] = Wv[i];
    W[3][i >> 7][i & 127] = Ws[i];
  }
  for (int i = tid; i < 128; i += 256) {
    B[0][i] = bq[i]; B[1][i] = bk[i]; B[2][i] = bv[i]; B[3][i] = bs[i];
  }
  __syncthreads();
  int gid = blockIdx.x * 256 + tid;
  int n = gid >> 7, c = gid & 127;
  if (n >= N) return;
  float x0 = x[n * 4 + 0], x1 = x[n * 4 + 1], x2 = x[n * 4 + 2], x3 = x[n * 4 + 3];
  float qv = x0 * W[0][0][c] + x1 * W[0][1][c] + x2 * W[0][2][c] + x3 * W[0][3][c] + B[0][c];
  float kv = x0 * W[1][0][c] + x1 * W[1][1][c] + x2 * W[1][2][c] + x3 * W[1][3][c] + B[1][c];
  float vv = x0 * W[2][0][c] + x1 * W[2][1][c] + x2 * W[2][2][c] + x3 * W[2][3][c] + B[2][c];
  float sv = x0 * W[3][0][c] + x1 * W[3][1][c] + x2 * W[3][2][c] + x3 * W[3][3][c] + B[3][c];
  q[(size_t)n * 128 + c] = f2bf(qv * QSCALE);
  kvb[(size_t)n * 256 + c]       = f2bf(kv);
  kvb[(size_t)n * 256 + 128 + c] = f2bf(vv);
  hs[(size_t)n * 128 + c] = f2bf(sv);
}

// ============== W -> bf16 transposed: wt[z][c][k] = W_z[k][c] =============
__global__ void prep_w(const float* __restrict__ Wq, const float* __restrict__ Wk,
                       const float* __restrict__ Wv, const float* __restrict__ Ws,
                       ushort* __restrict__ wt) {
  int idx = blockIdx.x * 256 + threadIdx.x;  // 4*16384
  int z = idx >> 14, rem = idx & 16383;
  int k_ = rem >> 7, c_ = rem & 127;
  const float* W = (z == 0) ? Wq : (z == 1) ? Wk : (z == 2) ? Wv : Ws;
  wt[z * 16384 + c_ * 128 + k_] = f2bf(W[k_ * 128 + c_]);
}

// ==== layers 1-2 GEMM via MFMA, z on grid, A input bf16, skip out bf16 ===
#define LDA 136
__global__ __launch_bounds__(256) void gemm_mfma(
    const ushort* __restrict__ H16, const ushort* __restrict__ wtg,
    const float* __restrict__ bq, const float* __restrict__ bk,
    const float* __restrict__ bv, const float* __restrict__ bs,
    ushort* __restrict__ q, ushort* __restrict__ kvb,
    ushort* __restrict__ hs, int N) {
  int z = blockIdx.z;
  const float* bb = (z == 0) ? bq : (z == 1) ? bk : (z == 2) ? bv : bs;
  __shared__ ushort Alds[64 * LDA];
  __shared__ ushort Wlds[128 * LDA];
  int tid = threadIdx.x;
  int n0 = blockIdx.x * 64;

  {
    const uint* wg = (const uint*)(wtg + z * 16384);
    uint* wl = (uint*)Wlds;
    for (int i = tid; i < 8192; i += 256) {
      int c_ = i >> 6, kp = i & 63;
      wl[c_ * (LDA / 2) + kp] = wg[c_ * 64 + kp];
    }
  }
  {  // A tile: direct bf16 copy (no conversion)
    const uint* hg = (const uint*)H16;
    uint* al = (uint*)Alds;
    for (int i = tid; i < 4096; i += 256) {
      int r = i >> 6, kp = i & 63;
      int grow = n0 + r; grow = (grow < N) ? grow : (N - 1);
      al[r * (LDA / 2) + kp] = hg[(size_t)grow * 64 + kp];
    }
  }
  __syncthreads();

  int w = tid >> 6, lane = tid & 63;
  int m_ = lane & 15, quad = lane >> 4;
  f32x4 acc[8];
#pragma unroll
  for (int ct = 0; ct < 8; ct++) acc[ct] = 0.f;

#pragma unroll
  for (int kc = 0; kc < 4; kc++) {
    short8 af = *(const short8*)&Alds[(w * 16 + m_) * LDA + kc * 32 + quad * 8];
#pragma unroll
    for (int ct = 0; ct < 8; ct++) {
      short8 bf = *(const short8*)&Wlds[(ct * 16 + m_) * LDA + kc * 32 + quad * 8];
      acc[ct] = __builtin_amdgcn_mfma_f32_16x16x32_bf16(af, bf, acc[ct], 0, 0, 0);
    }
  }

#pragma unroll
  for (int ct = 0; ct < 8; ct++) {
    int col = ct * 16 + m_;
    float bcol = bb[col];
#pragma unroll
    for (int reg = 0; reg < 4; reg++) {
      int n = n0 + w * 16 + quad * 4 + reg;
      if (n < N) {
        float o = acc[ct][reg] + bcol;
        if (z == 0)      q[(size_t)n * 128 + col] = f2bf(o * QSCALE);
        else if (z == 3) hs[(size_t)n * 128 + col] = f2bf(o);
        else             kvb[(size_t)n * 256 + ((z == 2) ? 128 : 0) + col] = f2bf(o);
      }
    }
  }
}

// ====== fused attention v12 (round-9 best): all-bf16 h streams + 2-edge ILP
__global__ __launch_bounds__(256) void attn_fused(
    const ushort* __restrict__ q, const ushort* __restrict__ kv,
    const int* __restrict__ indptr, const float4* __restrict__ csr_sa,
    const float* __restrict__ We,
    const ushort* __restrict__ hskip, ushort* __restrict__ hout, int N) {
  __shared__ float WeS[384];
  int tid = threadIdx.x;
  for (int i = tid; i < 384; i += 256) WeS[i] = We[i];
  __syncthreads();
  int lane = tid & 63;
  int n = blockIdx.x * 4 + (tid >> 6);
  if (n >= N) return;
  int g = lane >> 4, gl = lane & 15;
  int c = gl * 8;  // 8 channels per lane
  // q is bf16, already scaled by log2(e)/sqrt(128)
  uint4 qr = *(const uint4*)&q[(size_t)n * 128 + c];
  float qv[8] = {bflo(qr.x), bfhi(qr.x), bflo(qr.y), bfhi(qr.y),
                 bflo(qr.z), bfhi(qr.z), bflo(qr.w), bfhi(qr.w)};
  float we0[8], we1[8], we2[8];
#pragma unroll
  for (int j = 0; j < 8; j++) {
    we0[j] = WeS[c + j]; we1[j] = WeS[128 + c + j]; we2[j] = WeS[256 + c + j];
  }
  // t = We^T (S*q)  (identical in all 4 groups)
  float t0 = 0.f, t1 = 0.f, t2 = 0.f;
#pragma unroll
  for (int j = 0; j < 8; j++) {
    t0 = fmaf(we0[j], qv[j], t0);
    t1 = fmaf(we1[j], qv[j], t1);
    t2 = fmaf(we2[j], qv[j], t2);
  }
#pragma unroll
  for (int off = 1; off < 16; off <<= 1) {
    t0 += __shfl_xor(t0, off);
    t1 += __shfl_xor(t1, off);
    t2 += __shfl_xor(t2, off);
  }

  uint4 skr = *(const uint4*)&hskip[(size_t)n * 128 + c];
  float sk[8] = {bflo(skr.x), bfhi(skr.x), bflo(skr.y), bfhi(skr.y),
                 bflo(skr.z), bfhi(skr.z), bflo(skr.w), bfhi(skr.w)};
  int beg = indptr[n], end = indptr[n + 1];

  if (end > beg) {
    float d = 0.f;
    float sa0 = 0.f, sa1 = 0.f, sa2 = 0.f;
    float acc[8];
#pragma unroll
    for (int j = 0; j < 8; j++) acc[j] = 0.f;
    const uint* kvw = (const uint*)kv;
    const int endm1 = end - 1;

    // branch-free prefetch for edge pair (i, i+4), indices clamped in-bounds
    int i = beg + g;
    int pA = (i     < end) ? i     : endm1;
    int pB = (i + 4 < end) ? i + 4 : endm1;
    float4 saA = csr_sa[pA];
    float4 saB = csr_sa[pB];

    for (; i < end; i += 8) {
      float4 saAc = saA, saBc = saB;
      float wB = ((i + 4) < end) ? 1.f : 0.f;
      // prefetch next pair (always valid clamped indices, no branches)
      int nn = i + 8;
      int qA = (nn     < end) ? nn     : endm1;
      int qB = (nn + 4 < end) ? nn + 4 : endm1;
      saA = csr_sa[qA];
      saB = csr_sa[qB];
      int sjAc = __float_as_int(saAc.w);
      int sjBc = __float_as_int(saBc.w);
      // issue all 4 row loads up front (2 edges x K,V)
      const uint4* kpA = (const uint4*)(kvw + (size_t)sjAc * 128);
      const uint4* kpB = (const uint4*)(kvw + (size_t)sjBc * 128);
      uint4 krA = kpA[gl];
      uint4 krB = kpB[gl];
      uint4 vrA = kpA[16 + gl];
      uint4 vrB = kpB[16 + gl];
      float kxA[8], kxB[8];
      kxA[0] = bflo(krA.x); kxA[1] = bfhi(krA.x); kxA[2] = bflo(krA.y); kxA[3] = bfhi(krA.y);
      kxA[4] = bflo(krA.z); kxA[5] = bfhi(krA.z); kxA[6] = bflo(krA.w); kxA[7] = bfhi(krA.w);
      kxB[0] = bflo(krB.x); kxB[1] = bfhi(krB.x); kxB[2] = bflo(krB.y); kxB[3] = bfhi(krB.y);
      kxB[4] = bflo(krB.z); kxB[5] = bfhi(krB.z); kxB[6] = bflo(krB.w); kxB[7] = bfhi(krB.w);
      float pAv = 0.f, pBv = 0.f;
#pragma unroll
      for (int j = 0; j < 8; j++) {
        pAv = fmaf(qv[j], kxA[j], pAv);
        pBv = fmaf(qv[j], kxB[j], pBv);
      }
      // two independent 4-step reductions, interleaved
      pAv += __shfl_xor(pAv, 1);  pBv += __shfl_xor(pBv, 1);
      pAv += __shfl_xor(pAv, 2);  pBv += __shfl_xor(pBv, 2);
      pAv += __shfl_xor(pAv, 4);  pBv += __shfl_xor(pBv, 4);
      pAv += __shfl_xor(pAv, 8);  pBv += __shfl_xor(pBv, 8);
      pAv = fmaf(saAc.x, t0, pAv);
      pBv = fmaf(saBc.x, t0, pBv);
      pAv = fmaf(saAc.y, t1, pAv);
      pBv = fmaf(saBc.y, t1, pBv);
      pAv = fmaf(saAc.z, t2, pAv);
      pBv = fmaf(saBc.z, t2, pBv);
      float aA = __builtin_amdgcn_exp2f(pAv);
      float aB = wB * __builtin_amdgcn_exp2f(pBv);  // tail-B contributes 0
      d += aA + aB;
      sa0 = fmaf(aA, saAc.x, sa0); sa0 = fmaf(aB, saBc.x, sa0);
      sa1 = fmaf(aA, saAc.y, sa1); sa1 = fmaf(aB, saBc.y, sa1);
      sa2 = fmaf(aA, saAc.z, sa2); sa2 = fmaf(aB, saBc.z, sa2);
      float vxA[8], vxB[8];
      vxA[0] = bflo(vrA.x); vxA[1] = bfhi(vrA.x); vxA[2] = bflo(vrA.y); vxA[3] = bfhi(vrA.y);
      vxA[4] = bflo(vrA.z); vxA[5] = bfhi(vrA.z); vxA[6] = bflo(vrA.w); vxA[7] = bfhi(vrA.w);
      vxB[0] = bflo(vrB.x); vxB[1] = bfhi(vrB.x); vxB[2] = bflo(vrB.y); vxB[3] = bfhi(vrB.y);
      vxB[4] = bflo(vrB.z); vxB[5] = bfhi(vrB.z); vxB[6] = bflo(vrB.w); vxB[7] = bfhi(vrB.w);
#pragma unroll
      for (int j = 0; j < 8; j++) {
        acc[j] = fmaf(aA, vxA[j], acc[j]);
        acc[j] = fmaf(aB, vxB[j], acc[j]);
      }
    }
    // merge the 4 groups' partial sums (pure adds — no rescale needed)
#pragma unroll
    for (int off = 16; off < 64; off <<= 1) {
      d += __shfl_xor(d, off);
      sa0 += __shfl_xor(sa0, off);
      sa1 += __shfl_xor(sa1, off);
      sa2 += __shfl_xor(sa2, off);
#pragma unroll
      for (int j = 0; j < 8; j++) acc[j] += __shfl_xor(acc[j], off);
    }
    float inv = 1.f / d;
#pragma unroll
    for (int j = 0; j < 8; j++) {
      float ecorr = sa0 * we0[j] + sa1 * we1[j] + sa2 * we2[j];
      sk[j] += (acc[j] + ecorr) * inv;
    }
  }
#pragma unroll
  for (int j = 0; j < 8; j++) sk[j] = (sk[j] > 0.f) ? sk[j] : 0.01f * sk[j];
  if (g == 0) {
    uint4 hb;
    hb.x = pack2bf(sk[0], sk[1]);
    hb.y = pack2bf(sk[2], sk[3]);
    hb.z = pack2bf(sk[4], sk[5]);
    hb.w = pack2bf(sk[6], sk[7]);
    *(uint4*)&hout[(size_t)n * 128 + c] = hb;
  }
}

// ======================= pool (batch is sorted, bf16 input) =============
__global__ void pool_kernel(const ushort* __restrict__ h16, const int* __restrict__ batch,
                            float* __restrict__ gout, int N) {
  int tid = threadIdx.x;
  int sub = tid >> 6;
  int c = 2 * (tid & 63);
  int n0 = blockIdx.x * 64 + sub * 16;
  if (n0 >= N) return;
  int n1 = min(n0 + 16, N);
  float a0 = 0.f, a1 = 0.f;
  int cur = batch[n0];
  for (int n = n0; n < n1; n++) {
    int b = batch[n];
    if (b != cur) {
      atomicAdd(&gout[cur * 128 + c], a0);
      atomicAdd(&gout[cur * 128 + c + 1], a1);
      a0 = 0.f; a1 = 0.f; cur = b;
    }
    uint hv = *(const uint*)&h16[(size_t)n * 128 + c];
    a0 += bflo(hv); a1 += bfhi(hv);
  }
  atomicAdd(&gout[cur * 128 + c], a0);
  atomicAdd(&gout[cur * 128 + c + 1], a1);
}

// ===================== fused MLP head (one block / graph) ================
__global__ __launch_bounds__(256) void mlp_fused(
    const float* __restrict__ gp,
    const float* __restrict__ Wl0, const float* __restrict__ bl0,
    const float* __restrict__ Wl1, const float* __restrict__ bl1,
    const float* __restrict__ Wl2, const float* __restrict__ bl2,
    float* __restrict__ out) {
  int g = blockIdx.x;
  int tid = threadIdx.x;
  __shared__ float xin[CDIM];
  __shared__ float h1[L0DIM];
  __shared__ float h2[L1DIM];
  __shared__ float r0s[4], r1s[4];
  if (tid < CDIM) xin[tid] = gp[g * CDIM + tid];
  __syncthreads();
  for (int c = tid; c < L0DIM; c += 256) {
    float a0 = 0.f, a1 = 0.f, a2 = 0.f, a3 = 0.f;
#pragma unroll 4
    for (int kk = 0; kk < CDIM; kk += 4) {
      a0 = fmaf(xin[kk + 0], Wl0[(kk + 0) * L0DIM + c], a0);
      a1 = fmaf(xin[kk + 1], Wl0[(kk + 1) * L0DIM + c], a1);
      a2 = fmaf(xin[kk + 2], Wl0[(kk + 2) * L0DIM + c], a2);
      a3 = fmaf(xin[kk + 3], Wl0[(kk + 3) * L0DIM + c], a3);
    }
    h1[c] = fmaxf((a0 + a1) + (a2 + a3) + bl0[c], 0.f);
  }
  __syncthreads();
  {
    int c = tid;
    float a0 = 0.f, a1 = 0.f, a2 = 0.f, a3 = 0.f;
#pragma unroll 4
    for (int kk = 0; kk < L0DIM; kk += 4) {
      a0 = fmaf(h1[kk + 0], Wl1[(kk + 0) * L1DIM + c], a0);
      a1 = fmaf(h1[kk + 1], Wl1[(kk + 1) * L1DIM + c], a1);
      a2 = fmaf(h1[kk + 2], Wl1[(kk + 2) * L1DIM + c], a2);
      a3 = fmaf(h1[kk + 3], Wl1[(kk + 3) * L1DIM + c], a3);
    }
    h2[c] = fmaxf((a0 + a1) + (a2 + a3) + bl1[c], 0.f);
  }
  __syncthreads();
  float p0 = h2[tid] * Wl2[tid * 2 + 0];
  float p1 = h2[tid] * Wl2[tid * 2 + 1];
#pragma unroll
  for (int off = 32; off > 0; off >>= 1) {
    p0 += __shfl_down(p0, off);
    p1 += __shfl_down(p1, off);
  }
  int wv = tid >> 6, ln = tid & 63;
  if (ln == 0) { r0s[wv] = p0; r1s[wv] = p1; }
  __syncthreads();
  if (tid == 0) out[g * 2 + 0] = r0s[0] + r0s[1] + r0s[2] + r0s[3] + bl2[0];
  if (tid == 1) out[g * 2 + 1] = r1s[0] + r1s[1] + r1s[2] + r1s[3] + bl2[1];
}

// ============================== launch ==================================
extern "C" void kernel_launch(void* const* d_in, const int* in_sizes, int n_in,
                              void* d_out, int out_size, void* d_ws, size_t ws_size,
                              hipStream_t stream) {
  const int N = N_NODES, E = N_EDGES;
  const float* x    = (const float*)d_in[0];
  const int*   ei   = (const int*)d_in[1];
  const float* attr = (const float*)d_in[2];
  const int*   batch= (const int*)d_in[3];
  const int* src = ei;
  const int* dst = ei + E;

  const float *Wq0 = (const float*)d_in[4],  *bq0 = (const float*)d_in[5];
  const float *Wk0 = (const float*)d_in[6],  *bk0 = (const float*)d_in[7];
  const float *Wv0 = (const float*)d_in[8],  *bv0 = (const float*)d_in[9];
  const float *We0 = (const float*)d_in[10];
  const float *Ws0 = (const float*)d_in[11], *bs0 = (const float*)d_in[12];
  const float *Wq1 = (const float*)d_in[13], *bq1 = (const float*)d_in[14];
  const float *Wk1 = (const float*)d_in[15], *bk1 = (const float*)d_in[16];
  const float *Wv1 = (const float*)d_in[17], *bv1 = (const float*)d_in[18];
  const float *We1 = (const float*)d_in[19];
  const float *Ws1 = (const float*)d_in[20], *bs1 = (const float*)d_in[21];
  const float *Wl0 = (const float*)d_in[22], *bl0 = (const float*)d_in[23];
  const float *Wl1 = (const float*)d_in[24], *bl1 = (const float*)d_in[25];
  const float *Wl2 = (const float*)d_in[26], *bl2 = (const float*)d_in[27];

  size_t off = 0;
  auto carve = [&](size_t bytes) {
    void* p = (char*)d_ws + off;
    off += (bytes + 255) & ~(size_t)255;
    return p;
  };
  ushort* hsA      = (ushort*)carve((size_t)N * CDIM * 2);  // skip (bf16)
  ushort* hsB      = (ushort*)carve((size_t)N * CDIM * 2);
  ushort* hA16     = (ushort*)carve((size_t)N * CDIM * 2);  // h (bf16)
  ushort* hB16     = (ushort*)carve((size_t)N * CDIM * 2);
  ushort* qb       = (ushort*)carve((size_t)N * CDIM * 2);
  ushort* kvb      = (ushort*)carve((size_t)N * 256 * 2);
  int*    indptr   = (int*)carve((size_t)(N + 1) * 4);
  float4* csr_sa   = (float4*)carve((size_t)E * 16);
  int*    cc       = (int*)carve((size_t)2 * N * 4);   // counts | cursor
  int*    counts   = cc;
  int*    cursor   = cc + N;
  int*    excl     = (int*)carve((size_t)N * 4);
  int*    bsums    = (int*)carve((size_t)64 * 4);
  ushort* wt1      = (ushort*)carve((size_t)4 * 16384 * 2);
  float*  gp       = (float*)carve((size_t)GDIM * CDIM * 4);

  hipMemsetAsync(counts, 0, (size_t)N * 4, stream);

  int nscan = (N + 1023) / 1024;
  hist_kernel<<<(E + 255) / 256, 256, 0, stream>>>(dst, counts, E);
  scan_blocks<<<nscan, 1024, 0, stream>>>(counts, excl, bsums, N);
  scan_add<<<nscan, 1024, 0, stream>>>(excl, bsums, indptr, cursor, gp, N, E);
  scatter2_kernel<<<(E + 255) / 256, 256, 0, stream>>>(dst, src, attr, indptr, cursor,
                                                       csr_sa, E);
  prep_w<<<256, 256, 0, stream>>>(Wq1, Wk1, Wv1, Ws1, wt1);

  int naBlocks = (N + 3) / 4;
  dim3 gemmGrid((N + 63) / 64, 1, 4);

  // ---- layer 0 (din=4) ----
  l0_qkvs<<<(N * 128 + 255) / 256, 256, 0, stream>>>(
      x, Wq0, bq0, Wk0, bk0, Wv0, bv0, Ws0, bs0, qb, kvb, hsA, N);
  attn_fused<<<naBlocks, 256, 0, stream>>>(qb, kvb, indptr, csr_sa, We0, hsA, hA16, N);

  // ---- layer 1 (shared weights) ----
  gemm_mfma<<<gemmGrid, 256, 0, stream>>>(hA16, wt1, bq1, bk1, bv1, bs1, qb, kvb, hsB, N);
  attn_fused<<<naBlocks, 256, 0, stream>>>(qb, kvb, indptr, csr_sa, We1, hsB, hB16, N);

  // ---- layer 2 (same weights) ----
  gemm_mfma<<<gemmGrid, 256, 0, stream>>>(hB16, wt1, bq1, bk1, bv1, bs1, qb, kvb, hsA, N);
  attn_fused<<<naBlocks, 256, 0, stream>>>(qb, kvb, indptr, csr_sa, We1, hsA, hA16, N);

  // ---- pool + fused MLP ----
  pool_kernel<<<(N + 63) / 64, 256, 0, stream>>>(hA16, batch, gp, N);
  mlp_fused<<<GDIM, 256, 0, stream>>>(gp, Wl0, bl0, Wl1, bl1, Wl2, bl2, (float*)d_out);
}